// Round 12
// baseline (327.899 us; speedup 1.0000x reference)
//
#include <hip/hip_runtime.h>
#include <hip/hip_cooperative_groups.h>
#include <math.h>

namespace cg = cooperative_groups;

#define TOPK_K 10
#define EPS_F 1e-9f
#define IOU_EPS_F 1e-7f
#define CH 128          // anchors per assign tile
#define CCH 256         // anchors per collect tile
#define MGMAX 32        // max GTs per collect m-group
#define GRID_B 768      // 3 blocks/CU on 256 CUs -> co-resident (12.3KB LDS, 12 waves/CU)

struct Iou6 { float ov; float ov6; };

// NOTE: contract(off) so all phases compute bit-identical IoU/align values.
__device__ __forceinline__ Iou6 iou_pow6(float px1, float py1, float px2, float py2,
                                         float gx1, float gy1, float gx2, float gy2) {
#pragma clang fp contract(off)
  float ix1 = fmaxf(px1, gx1);
  float iy1 = fmaxf(py1, gy1);
  float ix2 = fminf(px2, gx2);
  float iy2 = fminf(py2, gy2);
  float dw = fmaxf(ix2 - ix1, 0.0f);
  float dh = fmaxf(iy2 - iy1, 0.0f);
  float inter = dw * dh;
  float a1 = (px2 - px1) * (py2 - py1);
  float a2 = (gx2 - gx1) * (gy2 - gy1);
  float den = a1 + a2 - inter + IOU_EPS_F;
  float iou = inter / den;
  float ov = fmaxf(iou, 0.0f);
  float ov2 = ov * ov;
  Iou6 r; r.ov = ov; r.ov6 = ov2 * ov2 * ov2;
  return r;
}

__device__ __forceinline__ float sigmoid_f(float x) {
#pragma clang fp contract(off)
  return 1.0f / (1.0f + expf(-x));
}

// key: (ordered float bits << 32) | ~idx  -- larger = (bigger v, smaller idx).
__device__ __forceinline__ unsigned long long mk_key(float v, int idx) {
  if (idx < 0) return 0ull;
  unsigned uv = __float_as_uint(v) | 0x80000000u;
  return ((unsigned long long)uv << 32) | (unsigned)(~idx);
}

// stable top-10 key-ladder insert, all static indices (stays in VGPRs)
#define KINSERT(kk)                                                      \
  if ((kk) > kl[9]) {                                                    \
    _Pragma("unroll")                                                    \
    for (int j = 9; j >= 1; --j) {                                       \
      if ((kk) > kl[j - 1])      kl[j] = kl[j - 1];                      \
      else if ((kk) > kl[j])     kl[j] = (kk);                           \
    }                                                                    \
    if ((kk) > kl[0]) kl[0] = (kk);                                      \
  }

#define WAVE_MERGE10()                                                         \
  {                                                                            \
    _Pragma("unroll")                                                          \
    for (int r = 0; r < TOPK_K; ++r) {                                         \
      unsigned long long kmine = kl[0], kw = kl[0];                            \
      _Pragma("unroll")                                                        \
      for (int off = 32; off > 0; off >>= 1) {                                 \
        unsigned long long o = __shfl_xor(kw, off);                            \
        if (o > kw) kw = o;                                                    \
      }                                                                        \
      if (lane == 0) skey[wid * TOPK_K + r] = kw;                              \
      if (kmine == kw && kw != 0ull) {                                         \
        _Pragma("unroll")                                                      \
        for (int j = 0; j < TOPK_K - 1; ++j) kl[j] = kl[j + 1];                \
        kl[TOPK_K - 1] = 0ull;                                                 \
      }                                                                        \
    }                                                                          \
  }

#define FINAL_MERGE10()                                                        \
  {                                                                            \
    _Pragma("unroll")                                                          \
    for (int r = 0; r < TOPK_K; ++r) {                                         \
      unsigned long long kmine = kl[0], kw = kl[0];                            \
      _Pragma("unroll")                                                        \
      for (int off = 32; off > 0; off >>= 1) {                                 \
        unsigned long long o = __shfl_xor(kw, off);                            \
        if (o > kw) kw = o;                                                    \
      }                                                                        \
      if (r == 0) maxv = __uint_as_float((unsigned)(kw >> 32) & 0x7fffffffu);  \
      if (r == TOPK_K - 1) {                                                   \
        Tv = __uint_as_float((unsigned)(kw >> 32) & 0x7fffffffu);              \
        Ti = (int)~(unsigned)(kw & 0xffffffffu);                               \
      }                                                                        \
      if (kmine == kw && kw != 0ull) {                                         \
        _Pragma("unroll")                                                      \
        for (int j = 0; j < TOPK_K - 1; ++j) kl[j] = kl[j + 1];                \
        kl[TOPK_K - 1] = 0ull;                                                 \
      }                                                                        \
    }                                                                          \
  }

// ---------------------------------------------------------------------------
// ONE cooperative kernel: zero -> collect -> select -> assign, grid.sync()
// between phases. Removes 3 graph-node boundaries + the zero kernel, and
// makes the dispatch big enough to appear in rocprof's top-5.
// ---------------------------------------------------------------------------
__launch_bounds__(256)
__global__ void k_fused(const float* __restrict__ pd_scores,
                        const float* __restrict__ pd_bboxes,
                        const float* __restrict__ anchors,
                        const int*   __restrict__ gt_labels,
                        const float* __restrict__ gt_bboxes,
                        const float* __restrict__ mask_gt,
                        int B, int N, int M, int C, int CAP, int MGS, int MGRP,
                        int*    __restrict__ cnt,
                        float2* __restrict__ lists,
                        float* __restrict__ maxv_g,
                        float* __restrict__ t10v_g,
                        int*   __restrict__ t10i_g,
                        float* __restrict__ out)
{
  cg::grid_group grid = cg::this_grid();
  const int tid  = threadIdx.x;
  const int lane = tid & 63;
  const int wid  = tid >> 6;
  const int nb   = gridDim.x;
  const int BM   = B * M;

  // collect-phase LDS
  __shared__ float4             csgt[MGMAX];
  __shared__ int                csgl[MGMAX];
  __shared__ int                csmg[MGMAX];
  __shared__ unsigned long long sbal[CCH / 64][MGMAX];
  __shared__ int                wbase[CCH / 64][MGMAX];
  // select-phase LDS
  __shared__ unsigned long long skey[4 * TOPK_K];
  __shared__ int sfb;
  // assign-phase LDS
  __shared__ float4 asgt[128];
  __shared__ int    asgl[128];
  __shared__ float  asmg[128];
  __shared__ float  asmpg[128];
  __shared__ float  aspre[128];
  __shared__ float  asmT[128];
  __shared__ int    asmI[128];
  __shared__ int    askeep[128];
  __shared__ float  s_pov[CH];
  __shared__ int    s_parg[CH], s_pcnt[CH], s_pfirst[CH], s_pone[CH];
  __shared__ int    slab[CH];
  __shared__ float  ssv[CH];

  // ===== phase 0: zero cnt =====
  for (int i = blockIdx.x * 256 + tid; i < BM; i += nb * 256) cnt[i] = 0;
  grid.sync();

  // ===== phase 1: collect (b, m-group, anchor-chunk tiles, block-stride) =====
  if (CAP > 0) {
    const int nchunk = (N + CCH - 1) / CCH;
    const int ntile  = nchunk * MGRP * B;
    for (int t = blockIdx.x; t < ntile; t += nb) {
      const int chunk = t % nchunk;
      const int rest  = t / nchunk;
      const int mg    = rest % MGRP;
      const int b     = rest / MGRP;
      const int m0 = mg * MGS;
      const int mcount = min(MGS, M - m0);
      if (mcount <= 0) continue;

      __syncthreads();   // protect csgt/sbal from previous tile
      if (tid < mcount) {
        csgt[tid] = *(const float4*)(gt_bboxes + (size_t)(b * M + m0 + tid) * 4);
        csgl[tid] = min(max(gt_labels[b * M + m0 + tid], 0), C - 1);
        csmg[tid] = (mask_gt[b * M + m0 + tid] > 0.0f) ? 1 : 0;
      }
      __syncthreads();

      const int n = chunk * CCH + tid;
      float4 p = make_float4(-1.f, -1.f, -2.f, -2.f);   // never overlaps
      if (n < N) p = *(const float4*)(pd_bboxes + ((size_t)b * N + n) * 4);

      for (int mi = 0; mi < mcount; ++mi) {
        const float4 g = csgt[mi];
        bool pred = false;
        if (csmg[mi]) {
          float ix1 = fmaxf(p.x, g.x), iy1 = fmaxf(p.y, g.y);
          float ix2 = fminf(p.z, g.z), iy2 = fminf(p.w, g.w);
          pred = (ix2 > ix1) && (iy2 > iy1);
        }
        unsigned long long bal = __ballot(pred);
        if (lane == 0) sbal[wid][mi] = bal;
      }
      __syncthreads();

      if (tid < mcount) {
        int t0 = __popcll(sbal[0][tid]), t1 = __popcll(sbal[1][tid]);
        int t2 = __popcll(sbal[2][tid]), t3 = __popcll(sbal[3][tid]);
        int tot = t0 + t1 + t2 + t3;
        int gb = (tot > 0) ? atomicAdd(&cnt[b * M + m0 + tid], tot) : 0;
        wbase[0][tid] = gb;
        wbase[1][tid] = gb + t0;
        wbase[2][tid] = gb + t0 + t1;
        wbase[3][tid] = gb + t0 + t1 + t2;
      }
      __syncthreads();

      const float* __restrict__ srow = pd_scores + ((size_t)b * N + n) * C;
      const unsigned long long ltm = (1ull << lane) - 1ull;
      for (int mi = 0; mi < mcount; ++mi) {
        unsigned long long bal = sbal[wid][mi];
        if (bal == 0ull) continue;
        if ((bal >> lane) & 1ull) {
          int pos = wbase[wid][mi] + __popcll(bal & ltm);
          if ((unsigned)pos < (unsigned)CAP) {
            const float4 g = csgt[mi];
            Iou6 io = iou_pow6(p.x, p.y, p.z, p.w, g.x, g.y, g.z, g.w);
            float a = sigmoid_f(srow[csgl[mi]]) * io.ov6;   // identical everywhere
            lists[(size_t)(b * M + m0 + mi) * CAP + pos] =
                make_float2(a, __int_as_float(n));
          }
        }
      }
    }
  }
  grid.sync();

  // ===== phase 2: select (one (b,m) row per block, block-stride) =====
  for (int r = blockIdx.x; r < BM; r += nb) {
    const int b = r / M;
    const int bm = r;

    if (mask_gt[bm] == 0.0f) {
      if (tid == 0) { maxv_g[bm] = 0.0f; t10v_g[bm] = 0.0f; t10i_g[bm] = -1; }
      continue;
    }

    unsigned long long kl[TOPK_K];
#pragma unroll
    for (int j = 0; j < TOPK_K; ++j) kl[j] = 0ull;

    float maxv = 0.0f, Tv = 0.0f; int Ti = -1;
    const int c = cnt[bm];
    bool fb = (CAP <= 0) || (c < TOPK_K) || (c > CAP);

    if (!fb) {
      const float2* __restrict__ lp = lists + (size_t)bm * CAP;
      for (int i = tid; i < c; i += 256) {
        float2 e = lp[i];
        unsigned long long k = mk_key(e.x, __float_as_int(e.y));
        KINSERT(k);
      }
      WAVE_MERGE10();
      __syncthreads();
      if (wid == 0) {
#pragma unroll
        for (int j = 0; j < TOPK_K; ++j) kl[j] = 0ull;
        kl[0] = (lane < 4 * TOPK_K) ? skey[lane] : 0ull;
        FINAL_MERGE10();
        if (lane == 0) sfb = (Tv == 0.0f) ? 1 : 0;
      }
      __syncthreads();
      fb = (sfb != 0);
    }

    if (fb) {
      // exact full-row scan (zeros included, keyed stable) — cold path
#pragma unroll
      for (int j = 0; j < TOPK_K; ++j) kl[j] = 0ull;
      const float4 g = *(const float4*)(gt_bboxes + (size_t)bm * 4);
      int gl = min(max(gt_labels[bm], 0), C - 1);
      const float* __restrict__ srow = pd_scores + (size_t)b * N * C;
      const float4* __restrict__ pb = (const float4*)(pd_bboxes + (size_t)b * N * 4);
      for (int n = tid; n < N; n += 256) {
        float4 p = pb[n];
        Iou6 io = iou_pow6(p.x, p.y, p.z, p.w, g.x, g.y, g.z, g.w);
        unsigned long long kub = mk_key(io.ov6, 0);
        if (kub > kl[TOPK_K - 1]) {
          float a = (io.ov6 == 0.0f) ? 0.0f
                                     : sigmoid_f(srow[(size_t)n * C + gl]) * io.ov6;
          unsigned long long k = mk_key(a, n);
          KINSERT(k);
        }
      }
      __syncthreads();
      WAVE_MERGE10();
      __syncthreads();
      if (wid == 0) {
#pragma unroll
        for (int j = 0; j < TOPK_K; ++j) kl[j] = 0ull;
        kl[0] = (lane < 4 * TOPK_K) ? skey[lane] : 0ull;
        FINAL_MERGE10();
      }
    }

    if (tid == 0) { maxv_g[bm] = maxv; t10v_g[bm] = Tv; t10i_g[bm] = Ti; }
  }
  grid.sync();

  // ===== phase 3: assign (128-anchor tiles x B, block-stride) =====
  {
    float* __restrict__ out_bbox   = out;
    float* __restrict__ out_scores = out + (size_t)B * N * 4;
    float* __restrict__ out_fg     = out_scores + (size_t)B * N * C;
    float* __restrict__ out_tgt    = out_fg + (size_t)B * N;

    const int achunks = (N + CH - 1) / CH;
    const int atiles = achunks * B;
    for (int t = blockIdx.x; t < atiles; t += nb) {
      const int ac = t % achunks;
      const int b  = t / achunks;
      const int chunk0 = ac * CH;
      const int al   = tid & (CH - 1);
      const int half = tid >> 7;
      const int n = chunk0 + al;

      __syncthreads();   // protect asgt/slab from previous tile
      if (tid < M) {
        asgt[tid] = *(const float4*)(gt_bboxes + (size_t)(b * M + tid) * 4);
        asgl[tid] = min(max(gt_labels[b * M + tid], 0), C - 1);
        asmg[tid] = mask_gt[b * M + tid];
        float mv  = maxv_g[b * M + tid];
        float mpg = fmaxf(mv, EPS_F);
        asmpg[tid] = mpg;
        aspre[tid] = mpg * 0.999999f;
        asmT[tid]  = t10v_g[b * M + tid];
        asmI[tid]  = t10i_g[b * M + tid];
        askeep[tid] = (mv > EPS_F) ? 1 : 0;
      }
      __syncthreads();

      const bool valid = (n < N);
      float pov = -1.0f; int parg = 0;
      int pcnt = 0, pfirst = -1, pone = 0;

      if (valid) {
        const float4 p = *(const float4*)(pd_bboxes + ((size_t)b * N + n) * 4);
        const float ax = anchors[(size_t)n * 2];
        const float ay = anchors[(size_t)n * 2 + 1];
        const float* __restrict__ srow = pd_scores + ((size_t)b * N + n) * C;

        const int mhalf = (M + 1) >> 1;
        const int mlo = half ? mhalf : 0;
        const int mhi = half ? M : mhalf;

        for (int m = mlo; m < mhi; ++m) {
          const float4 gbb = asgt[m];
          // fast-path: 94% of pairs don't intersect -> ov=0, ov6=0
          float ix1 = fmaxf(p.x, gbb.x), iy1 = fmaxf(p.y, gbb.y);
          float ix2 = fminf(p.z, gbb.z), iy2 = fminf(p.w, gbb.w);
          const bool ovl = (ix2 > ix1) && (iy2 > iy1);
          const float mgv = asmg[m];
          if (ovl) {
            Iou6 io = iou_pow6(p.x, p.y, p.z, p.w, gbb.x, gbb.y, gbb.z, gbb.w);
            if (io.ov > pov) { pov = io.ov; parg = m; }   // first-occurrence argmax
            if (mgv > 0.0f) {
              const float T = asmT[m];
              const int keep = askeep[m];
              bool mem = false;
              const bool cand = keep && (io.ov6 > T);
              if (cand || (io.ov6 >= aspre[m])) {
                const float a = sigmoid_f(srow[asgl[m]]) * io.ov6;
                if (cand) mem = (a > T) || (a == T && n <= asmI[m]);
                if (a / asmpg[m] >= 1.0f) pone = 1;
              } else if (keep && (T == 0.0f) && (io.ov6 == 0.0f)) {
                mem = (n <= asmI[m]);      // underflow-zero in top-10 tail
              }
              if (mem) {
                const float d = fminf(fminf(ax - gbb.x, ay - gbb.y),
                                      fminf(gbb.z - ax, gbb.w - ay));
                if (d > EPS_F) { pcnt++; if (pfirst < 0) pfirst = m; }
              }
            }
          } else {
            // ov=0 can't win argmax (pov>=0 after any overlap; all-zero row -> parg=0)
            if (mgv > 0.0f && askeep[m] && (asmT[m] == 0.0f) && (n <= asmI[m])) {
              const float d = fminf(fminf(ax - gbb.x, ay - gbb.y),
                                    fminf(gbb.z - ax, gbb.w - ay));
              if (d > EPS_F) { pcnt++; if (pfirst < 0) pfirst = m; }
            }
          }
        }
      }

      if (half == 1 && valid) {
        s_pov[al] = pov; s_parg[al] = parg; s_pcnt[al] = pcnt;
        s_pfirst[al] = pfirst; s_pone[al] = pone;
      }
      __syncthreads();

      if (half == 0 && valid) {
        float ov1 = s_pov[al];
        if (ov1 > pov) { pov = ov1; parg = s_parg[al]; }
        pcnt += s_pcnt[al];
        if (pfirst < 0) pfirst = s_pfirst[al];
        pone |= s_pone[al];

        float fg; int tgt;
        if (pcnt > 1)       { fg = 1.0f; tgt = parg; }
        else if (pcnt == 1) { fg = 1.0f; tgt = pfirst; }
        else                { fg = 0.0f; tgt = 0; }

        slab[al] = asgl[tgt];
        ssv[al]  = (fg > 0.0f && pone) ? 1.0f : 0.0f;

        *(float4*)(out_bbox + ((size_t)b * N + n) * 4) = asgt[tgt];
        out_fg[(size_t)b * N + n]  = fg;
        out_tgt[(size_t)b * N + n] = (float)tgt;
      }
      __syncthreads();

      const int rows = min(CH, N - chunk0);
      const int c4n = C >> 2;
      float4* __restrict__ os4 = (float4*)(out_scores + ((size_t)b * N + chunk0) * C);
      const int tot = rows * c4n;
      if (c4n == 20) {
        for (int i = tid; i < tot; i += 256) {
          unsigned row = __umulhi((unsigned)i, 0xCCCCCCCDu) >> 4;
          int c0 = (i - (int)row * 20) * 4;
          int lr = slab[row]; float v = ssv[row];
          float4 o;
          o.x = (c0     == lr) ? v : 0.0f;
          o.y = (c0 + 1 == lr) ? v : 0.0f;
          o.z = (c0 + 2 == lr) ? v : 0.0f;
          o.w = (c0 + 3 == lr) ? v : 0.0f;
          os4[i] = o;
        }
      } else {
        for (int i = tid; i < tot; i += 256) {
          int row = i / c4n;
          int c0 = (i - row * c4n) * 4;
          int lr = slab[row]; float v = ssv[row];
          float4 o;
          o.x = (c0     == lr) ? v : 0.0f;
          o.y = (c0 + 1 == lr) ? v : 0.0f;
          o.z = (c0 + 2 == lr) ? v : 0.0f;
          o.w = (c0 + 3 == lr) ? v : 0.0f;
          os4[i] = o;
        }
      }
    }
  }
}

extern "C" void kernel_launch(void* const* d_in, const int* in_sizes, int n_in,
                              void* d_out, int out_size, void* d_ws, size_t ws_size,
                              hipStream_t stream) {
  const float* pd_scores = (const float*)d_in[0];
  const float* pd_bboxes = (const float*)d_in[1];
  const float* anchors   = (const float*)d_in[2];
  const int*   gt_labels = (const int*)d_in[3];
  const float* gt_bboxes = (const float*)d_in[4];
  const float* mask_gt   = (const float*)d_in[5];

  int N = in_sizes[2] / 2;               // anchor_points (N,2)
  int B = in_sizes[1] / (N * 4);         // pd_bboxes (B,N,4)
  int M = in_sizes[3] / B;               // gt_labels (B,M,1)
  int C = in_sizes[0] / (B * N);         // pd_scores (B,N,C)
  const int BM = B * M;

  char* ws = (char*)d_ws;
  float*  maxv  = (float*)ws;  ws += (size_t)BM * 4;
  float*  t10v  = (float*)ws;  ws += (size_t)BM * 4;
  int*    t10i  = (int*)ws;    ws += (size_t)BM * 4;
  int*    cnt   = (int*)ws;    ws += (size_t)BM * 4;
  float2* lists = (float2*)ws;

  const size_t header = (size_t)BM * 16;
  size_t avail = (ws_size > header) ? (ws_size - header) : 0;
  long long capll = (long long)(avail / ((size_t)BM * 8));
  int CAP = (int)((capll > 4096) ? 4096 : capll);
  if (CAP < 512) CAP = 0;   // small ws: rows take exact fallback in select phase

  int MGRP = 8;
  int MGS  = (M + MGRP - 1) / MGRP;
  while (MGS > MGMAX) { MGRP *= 2; MGS = (M + MGRP - 1) / MGRP; }

  float* outp = (float*)d_out;
  void* args[] = {
    (void*)&pd_scores, (void*)&pd_bboxes, (void*)&anchors,
    (void*)&gt_labels, (void*)&gt_bboxes, (void*)&mask_gt,
    (void*)&B, (void*)&N, (void*)&M, (void*)&C,
    (void*)&CAP, (void*)&MGS, (void*)&MGRP,
    (void*)&cnt, (void*)&lists,
    (void*)&maxv, (void*)&t10v, (void*)&t10i,
    (void*)&outp
  };
  hipLaunchCooperativeKernel((const void*)k_fused, dim3(GRID_B), dim3(256),
                             args, 0, stream);
}

// Round 13
// 133.504 us; speedup vs baseline: 2.4561x; 2.4561x over previous
//
#include <hip/hip_runtime.h>
#include <math.h>

#define TOPK_K 10
#define EPS_F 1e-9f
#define IOU_EPS_F 1e-7f
#define CH 128          // anchors per k_assign block

struct Iou6 { float ov; float ov6; };

// NOTE: contract(off) so both kernels compute bit-identical IoU/align values.
// Membership (a==T) and the q>=1 test compare values computed in different
// kernels; any cross-kernel FMA-contraction difference would break equality.
__device__ __forceinline__ Iou6 iou_pow6(float px1, float py1, float px2, float py2,
                                         float gx1, float gy1, float gx2, float gy2) {
#pragma clang fp contract(off)
  float ix1 = fmaxf(px1, gx1);
  float iy1 = fmaxf(py1, gy1);
  float ix2 = fminf(px2, gx2);
  float iy2 = fminf(py2, gy2);
  float dw = fmaxf(ix2 - ix1, 0.0f);
  float dh = fmaxf(iy2 - iy1, 0.0f);
  float inter = dw * dh;
  float a1 = (px2 - px1) * (py2 - py1);
  float a2 = (gx2 - gx1) * (gy2 - gy1);
  float den = a1 + a2 - inter + IOU_EPS_F;
  float iou = inter / den;
  float ov = fmaxf(iou, 0.0f);
  float ov2 = ov * ov;
  Iou6 r; r.ov = ov; r.ov6 = ov2 * ov2 * ov2;
  return r;
}

__device__ __forceinline__ float sigmoid_f(float x) {
#pragma clang fp contract(off)
  return 1.0f / (1.0f + expf(-x));
}

// key: (ordered float bits << 32) | ~idx  -- larger = (bigger v, smaller idx).
// v >= 0 always; idx<0 -> sentinel key 0 (below every real key, incl. v==0).
__device__ __forceinline__ unsigned long long mk_key(float v, int idx) {
  if (idx < 0) return 0ull;
  unsigned uv = __float_as_uint(v) | 0x80000000u;
  return ((unsigned long long)uv << 32) | (unsigned)(~idx);
}

// stable top-10 key-ladder insert, all static indices (stays in VGPRs)
#define KINSERT(kk)                                                      \
  if ((kk) > kl[9]) {                                                    \
    _Pragma("unroll")                                                    \
    for (int j = 9; j >= 1; --j) {                                       \
      if ((kk) > kl[j - 1])      kl[j] = kl[j - 1];                      \
      else if ((kk) > kl[j])     kl[j] = (kk);                           \
    }                                                                    \
    if ((kk) > kl[0]) kl[0] = (kk);                                      \
  }

// 512-thread (8-wave) 10-round keyed merge: per round wave-reduce heads ->
// sred[8] -> block max -> unique owner pops. Sets maxv (r=0), Tv/Ti (r=9).
#define MERGE512()                                                             \
  {                                                                            \
    _Pragma("unroll")                                                          \
    for (int r = 0; r < TOPK_K; ++r) {                                         \
      unsigned long long kw = kl[0];                                           \
      _Pragma("unroll")                                                        \
      for (int off = 32; off > 0; off >>= 1) {                                 \
        unsigned long long o = __shfl_xor(kw, off);                            \
        if (o > kw) kw = o;                                                    \
      }                                                                        \
      if (lane == 0) sred[wid] = kw;                                           \
      __syncthreads();                                                         \
      unsigned long long kb = sred[0];                                         \
      _Pragma("unroll")                                                        \
      for (int w = 1; w < 8; ++w) { unsigned long long o = sred[w]; if (o > kb) kb = o; } \
      if (r == 0) maxv = __uint_as_float((unsigned)(kb >> 32) & 0x7fffffffu);  \
      if (r == TOPK_K - 1) {                                                   \
        Tv = __uint_as_float((unsigned)(kb >> 32) & 0x7fffffffu);              \
        Ti = (int)~(unsigned)(kb & 0xffffffffu);                               \
      }                                                                        \
      if (kl[0] == kb && kb != 0ull) {   /* unique owner (keys unique) */      \
        _Pragma("unroll")                                                      \
        for (int j = 0; j < TOPK_K - 1; ++j) kl[j] = kl[j + 1];                \
        kl[TOPK_K - 1] = 0ull;                                                 \
      }                                                                        \
      __syncthreads();                                                         \
    }                                                                          \
  }

// hot-path per-anchor step: 6-op overlap test skips ~94% of pairs entirely;
// zero-valued aligns are NOT inserted (handled by the Tv==0 rescan).
#define PROCA(p, nn)                                                           \
  {                                                                            \
    float ix1 = fmaxf((p).x, g.x), iy1 = fmaxf((p).y, g.y);                    \
    float ix2 = fminf((p).z, g.z), iy2 = fminf((p).w, g.w);                    \
    if (ix2 > ix1 && iy2 > iy1) {                                              \
      Iou6 io = iou_pow6((p).x, (p).y, (p).z, (p).w, g.x, g.y, g.z, g.w);      \
      if (mk_key(io.ov6, 0) > kl[TOPK_K - 1]) {  /* ub: key(a,n)<=key(ov6,0) */\
        float a = (io.ov6 == 0.0f) ? 0.0f                                      \
                  : sigmoid_f(srow[(size_t)(nn) * C + gl]) * io.ov6;           \
        if (a > 0.0f) { unsigned long long k = mk_key(a, (nn)); KINSERT(k); }  \
      }                                                                        \
    }                                                                          \
  }

// ---------------------------------------------------------------------------
// Kernel 1: one block (512 thr) per (b,m): maxv (top-1 align), (T,I) = 10th
// (value, index). Single pass, no atomics/lists/zeroing. Full keyed rescan
// (zeros included) when the 10th is zero-valued (row has <10 positive aligns).
// ---------------------------------------------------------------------------
__launch_bounds__(512)
__global__ void k_topk(const float* __restrict__ pd_scores,
                       const float* __restrict__ pd_bboxes,
                       const int*   __restrict__ gt_labels,
                       const float* __restrict__ gt_bboxes,
                       const float* __restrict__ mask_gt,
                       int B, int N, int M, int C,
                       float* __restrict__ maxv_out,   // [B*M]
                       float* __restrict__ t10v_out,   // [B*M]
                       int*   __restrict__ t10i_out)   // [B*M]
{
  const int m = blockIdx.x, b = blockIdx.y;
  const int bm = b * M + m;
  const int tid = threadIdx.x;
  const int lane = tid & 63;
  const int wid  = tid >> 6;

  __shared__ unsigned long long sred[8];
  __shared__ int sfb;

  if (mask_gt[bm] == 0.0f) {
    if (tid == 0) { maxv_out[bm] = 0.0f; t10v_out[bm] = 0.0f; t10i_out[bm] = -1; }
    return;
  }

  const float4 g = *(const float4*)(gt_bboxes + (size_t)bm * 4);
  const int gl = min(max(gt_labels[bm], 0), C - 1);
  const float* __restrict__ srow = pd_scores + (size_t)b * N * C;
  const float4* __restrict__ pb = (const float4*)(pd_bboxes + (size_t)b * N * 4);

  unsigned long long kl[TOPK_K];
#pragma unroll
  for (int j = 0; j < TOPK_K; ++j) kl[j] = 0ull;

  float maxv = 0.0f, Tv = 0.0f; int Ti = -1;

  // phase A: x4-unrolled scan, positives only
  int n = tid;
  for (; n + 3 * 512 < N; n += 4 * 512) {
    float4 p0 = pb[n];
    float4 p1 = pb[n + 512];
    float4 p2 = pb[n + 1024];
    float4 p3 = pb[n + 1536];
    PROCA(p0, n);
    PROCA(p1, n + 512);
    PROCA(p2, n + 1024);
    PROCA(p3, n + 1536);
  }
  for (; n < N; n += 512) {
    float4 p = pb[n];
    PROCA(p, n);
  }

  MERGE512();

  if (tid == 0) sfb = (Tv == 0.0f) ? 1 : 0;   // zeros reached the top-10
  __syncthreads();

  if (sfb) {
    // phase B (cold): exact full rescan with zero-valued entries included
#pragma unroll
    for (int j = 0; j < TOPK_K; ++j) kl[j] = 0ull;
    for (int n2 = tid; n2 < N; n2 += 512) {
      float4 p = pb[n2];
      Iou6 io = iou_pow6(p.x, p.y, p.z, p.w, g.x, g.y, g.z, g.w);
      unsigned long long kub = mk_key(io.ov6, 0);   // >= any key with value<=ov6
      if (kub > kl[TOPK_K - 1]) {
        float a = (io.ov6 == 0.0f) ? 0.0f
                                   : sigmoid_f(srow[(size_t)n2 * C + gl]) * io.ov6;
        unsigned long long k = mk_key(a, n2);
        KINSERT(k);
      }
    }
    MERGE512();
  }

  if (tid == 0) { maxv_out[bm] = maxv; t10v_out[bm] = Tv; t10i_out[bm] = Ti; }
}

// ---------------------------------------------------------------------------
// Kernel 2: per-anchor assignment + all outputs. R10 structure + the overlap
// fast-path refchecked in R12's fused phase 3. 256 thr = 128 anchors x 2
// m-halves; membership by rank test vs (T,I): a>T || (a==T && n<=I).
// ---------------------------------------------------------------------------
__launch_bounds__(256)
__global__ void k_assign(const float* __restrict__ pd_scores,
                         const float* __restrict__ pd_bboxes,
                         const float* __restrict__ anchors,
                         const int*   __restrict__ gt_labels,
                         const float* __restrict__ gt_bboxes,
                         const float* __restrict__ mask_gt,
                         const float* __restrict__ maxv_in,
                         const float* __restrict__ t10v_in,
                         const int*   __restrict__ t10i_in,
                         int B, int N, int M, int C,
                         float* __restrict__ out)
{
  const int b = blockIdx.y;
  const int chunk0 = blockIdx.x * CH;
  const int tid = threadIdx.x;
  const int al   = tid & (CH - 1);   // anchor-local
  const int half = tid >> 7;         // which m-half this thread covers
  const int n = chunk0 + al;

  __shared__ float4 sgt[128];
  __shared__ int    sgl[128];
  __shared__ float  smg[128];
  __shared__ float  smpg[128];
  __shared__ float  spre[128];
  __shared__ float  smT[128];
  __shared__ int    smI[128];
  __shared__ int    skeep[128];
  __shared__ float  s_pov[CH];
  __shared__ int    s_parg[CH], s_pcnt[CH], s_pfirst[CH], s_pone[CH];
  __shared__ int    slab[CH];
  __shared__ float  ssv[CH];

  if (tid < M) {
    sgt[tid] = *(const float4*)(gt_bboxes + (size_t)(b * M + tid) * 4);
    sgl[tid] = min(max(gt_labels[b * M + tid], 0), C - 1);
    smg[tid] = mask_gt[b * M + tid];
    float mv  = maxv_in[b * M + tid];
    float mpg = fmaxf(mv, EPS_F);       // clip(align.max, EPS)
    smpg[tid] = mpg;
    spre[tid] = mpg * 0.999999f;        // q>=1 prefilter (below any rounding)
    smT[tid]  = t10v_in[b * M + tid];
    smI[tid]  = t10i_in[b * M + tid];
    skeep[tid] = (mv > EPS_F) ? 1 : 0;  // keep = topk max > EPS
  }
  __syncthreads();

  float* __restrict__ out_bbox   = out;
  float* __restrict__ out_scores = out + (size_t)B * N * 4;
  float* __restrict__ out_fg     = out_scores + (size_t)B * N * C;
  float* __restrict__ out_tgt    = out_fg + (size_t)B * N;

  const bool valid = (n < N);
  float pov = -1.0f; int parg = 0;
  int pcnt = 0, pfirst = -1, pone = 0;

  if (valid) {
    const float4 p = *(const float4*)(pd_bboxes + ((size_t)b * N + n) * 4);
    const float ax = anchors[(size_t)n * 2];
    const float ay = anchors[(size_t)n * 2 + 1];
    const float* __restrict__ srow = pd_scores + ((size_t)b * N + n) * C;

    const int mhalf = (M + 1) >> 1;
    const int mlo = half ? mhalf : 0;
    const int mhi = half ? M : mhalf;

    for (int m = mlo; m < mhi; ++m) {
      const float4 gbb = sgt[m];
      // fast-path: ~94% of pairs don't intersect -> ov=0, ov6=0
      float ix1 = fmaxf(p.x, gbb.x), iy1 = fmaxf(p.y, gbb.y);
      float ix2 = fminf(p.z, gbb.z), iy2 = fminf(p.w, gbb.w);
      const bool ovl = (ix2 > ix1) && (iy2 > iy1);
      const float mgv = smg[m];
      if (ovl) {
        Iou6 io = iou_pow6(p.x, p.y, p.z, p.w, gbb.x, gbb.y, gbb.z, gbb.w);
        if (io.ov > pov) { pov = io.ov; parg = m; }   // first-occurrence argmax
        if (mgv > 0.0f) {
          const float T = smT[m];
          const int keep = skeep[m];
          bool mem = false;
          const bool cand = keep && (io.ov6 > T);     // align < ov6 (sig<1)
          if (cand || (io.ov6 >= spre[m])) {
            const float a = sigmoid_f(srow[sgl[m]]) * io.ov6;  // == k_topk's a
            if (cand) mem = (a > T) || (a == T && n <= smI[m]);
            if (a / smpg[m] >= 1.0f) pone = 1;        // int32(norm_align)==1
          } else if (keep && (T == 0.0f) && (io.ov6 == 0.0f)) {
            mem = (n <= smI[m]);                      // underflow-zero in tail
          }
          if (mem) {
            const float d = fminf(fminf(ax - gbb.x, ay - gbb.y),
                                  fminf(gbb.z - ax, gbb.w - ay));
            if (d > EPS_F) { pcnt++; if (pfirst < 0) pfirst = m; }
          }
        }
      } else {
        // ov==0 can't win argmax (all-zero row keeps parg=0, matching argmax)
        if (mgv > 0.0f && skeep[m] && (smT[m] == 0.0f) && (n <= smI[m])) {
          const float d = fminf(fminf(ax - gbb.x, ay - gbb.y),
                                fminf(gbb.z - ax, gbb.w - ay));
          if (d > EPS_F) { pcnt++; if (pfirst < 0) pfirst = m; }
        }
      }
    }
  }

  if (half == 1 && valid) {
    s_pov[al] = pov; s_parg[al] = parg; s_pcnt[al] = pcnt;
    s_pfirst[al] = pfirst; s_pone[al] = pone;
  }
  __syncthreads();

  if (half == 0 && valid) {
    // merge halves: half0 wins ov ties (lower m = first occurrence)
    float ov1 = s_pov[al];
    if (ov1 > pov) { pov = ov1; parg = s_parg[al]; }
    pcnt += s_pcnt[al];
    if (pfirst < 0) pfirst = s_pfirst[al];
    pone |= s_pone[al];

    float fg; int tgt;
    if (pcnt > 1)       { fg = 1.0f; tgt = parg; }     // where(multi, is_max, .)
    else if (pcnt == 1) { fg = 1.0f; tgt = pfirst; }
    else                { fg = 0.0f; tgt = 0; }        // argmax of zero row = 0

    slab[al] = sgl[tgt];
    ssv[al]  = (fg > 0.0f && pone) ? 1.0f : 0.0f;

    *(float4*)(out_bbox + ((size_t)b * N + n) * 4) = sgt[tgt];
    out_fg[(size_t)b * N + n]  = fg;
    out_tgt[(size_t)b * N + n] = (float)tgt;
  }
  __syncthreads();

  // cooperative coalesced write of the (rows x C) score tile
  const int rows = min(CH, N - chunk0);
  const int c4n = C >> 2;
  float4* __restrict__ os4 = (float4*)(out_scores + ((size_t)b * N + chunk0) * C);
  const int tot = rows * c4n;
  if (c4n == 20) {
    // C==80 fast path: i/20 via magic mul (runtime div = ~40-op libcall)
    for (int i = tid; i < tot; i += 256) {
      unsigned row = __umulhi((unsigned)i, 0xCCCCCCCDu) >> 4;
      int c0 = (i - (int)row * 20) * 4;
      int lr = slab[row]; float v = ssv[row];
      float4 o;
      o.x = (c0     == lr) ? v : 0.0f;
      o.y = (c0 + 1 == lr) ? v : 0.0f;
      o.z = (c0 + 2 == lr) ? v : 0.0f;
      o.w = (c0 + 3 == lr) ? v : 0.0f;
      os4[i] = o;
    }
  } else {
    for (int i = tid; i < tot; i += 256) {
      int row = i / c4n;
      int c0 = (i - row * c4n) * 4;
      int lr = slab[row]; float v = ssv[row];
      float4 o;
      o.x = (c0     == lr) ? v : 0.0f;
      o.y = (c0 + 1 == lr) ? v : 0.0f;
      o.z = (c0 + 2 == lr) ? v : 0.0f;
      o.w = (c0 + 3 == lr) ? v : 0.0f;
      os4[i] = o;
    }
  }
}

extern "C" void kernel_launch(void* const* d_in, const int* in_sizes, int n_in,
                              void* d_out, int out_size, void* d_ws, size_t ws_size,
                              hipStream_t stream) {
  const float* pd_scores = (const float*)d_in[0];
  const float* pd_bboxes = (const float*)d_in[1];
  const float* anchors   = (const float*)d_in[2];
  const int*   gt_labels = (const int*)d_in[3];
  const float* gt_bboxes = (const float*)d_in[4];
  const float* mask_gt   = (const float*)d_in[5];

  const int N = in_sizes[2] / 2;               // anchor_points (N,2)
  const int B = in_sizes[1] / (N * 4);         // pd_bboxes (B,N,4)
  const int M = in_sizes[3] / B;               // gt_labels (B,M,1)
  const int C = in_sizes[0] / (B * N);         // pd_scores (B,N,C)
  const int BM = B * M;

  char* ws = (char*)d_ws;
  float* maxv = (float*)ws;  ws += (size_t)BM * 4;
  float* t10v = (float*)ws;  ws += (size_t)BM * 4;
  int*   t10i = (int*)ws;

  dim3 g1(M, B);
  k_topk<<<g1, 512, 0, stream>>>(pd_scores, pd_bboxes, gt_labels, gt_bboxes,
                                 mask_gt, B, N, M, C, maxv, t10v, t10i);

  dim3 g2((N + CH - 1) / CH, B);
  k_assign<<<g2, 256, 0, stream>>>(pd_scores, pd_bboxes, anchors, gt_labels,
                                   gt_bboxes, mask_gt, maxv, t10v, t10i,
                                   B, N, M, C, (float*)d_out);
}

// Round 14
// 77.930 us; speedup vs baseline: 4.2076x; 1.7131x over previous
//
#include <hip/hip_runtime.h>
#include <math.h>

#define TOPK_K 10
#define EPS_F 1e-9f
#define IOU_EPS_F 1e-7f
#define CH 128          // anchors per k_assign block
#define CCH 256         // anchors per k_collect block
#define MG 12           // GTs per collect m-group (M=96 -> MGRP=8)
#define SCAP 96         // LDS staging entries per (block, m)

struct Iou6 { float ov; float ov6; };

// NOTE: contract(off) so all kernels compute bit-identical IoU/align values.
// Membership (a==T) and the q>=1 test compare values computed in different
// kernels; any cross-kernel FMA-contraction difference would break equality.
__device__ __forceinline__ Iou6 iou_pow6(float px1, float py1, float px2, float py2,
                                         float gx1, float gy1, float gx2, float gy2) {
#pragma clang fp contract(off)
  float ix1 = fmaxf(px1, gx1);
  float iy1 = fmaxf(py1, gy1);
  float ix2 = fminf(px2, gx2);
  float iy2 = fminf(py2, gy2);
  float dw = fmaxf(ix2 - ix1, 0.0f);
  float dh = fmaxf(iy2 - iy1, 0.0f);
  float inter = dw * dh;
  float a1 = (px2 - px1) * (py2 - py1);
  float a2 = (gx2 - gx1) * (gy2 - gy1);
  float den = a1 + a2 - inter + IOU_EPS_F;
  float iou = inter / den;
  float ov = fmaxf(iou, 0.0f);
  float ov2 = ov * ov;
  Iou6 r; r.ov = ov; r.ov6 = ov2 * ov2 * ov2;
  return r;
}

__device__ __forceinline__ float sigmoid_f(float x) {
#pragma clang fp contract(off)
  return 1.0f / (1.0f + expf(-x));
}

// key: (ordered float bits << 32) | ~idx  -- larger = (bigger v, smaller idx).
// v >= 0 always; idx<0 -> sentinel key 0 (below every real key, incl. v==0).
__device__ __forceinline__ unsigned long long mk_key(float v, int idx) {
  if (idx < 0) return 0ull;
  unsigned uv = __float_as_uint(v) | 0x80000000u;
  return ((unsigned long long)uv << 32) | (unsigned)(~idx);
}

// stable top-10 key-ladder insert, all static indices (stays in VGPRs)
#define KINSERT(kk)                                                      \
  if ((kk) > kl[9]) {                                                    \
    _Pragma("unroll")                                                    \
    for (int j = 9; j >= 1; --j) {                                       \
      if ((kk) > kl[j - 1])      kl[j] = kl[j - 1];                      \
      else if ((kk) > kl[j])     kl[j] = (kk);                           \
    }                                                                    \
    if ((kk) > kl[0]) kl[0] = (kk);                                      \
  }

// wave-stage: 10 rounds of 64-lane key max + pop -> skey[wid*10+r]
#define WAVE_MERGE10()                                                         \
  {                                                                            \
    _Pragma("unroll")                                                          \
    for (int r = 0; r < TOPK_K; ++r) {                                         \
      unsigned long long kmine = kl[0], kw = kl[0];                            \
      _Pragma("unroll")                                                        \
      for (int off = 32; off > 0; off >>= 1) {                                 \
        unsigned long long o = __shfl_xor(kw, off);                            \
        if (o > kw) kw = o;                                                    \
      }                                                                        \
      if (lane == 0) skey[wid * TOPK_K + r] = kw;                              \
      if (kmine == kw && kw != 0ull) {  /* unique owner pops */                \
        _Pragma("unroll")                                                      \
        for (int j = 0; j < TOPK_K - 1; ++j) kl[j] = kl[j + 1];                \
        kl[TOPK_K - 1] = 0ull;                                                 \
      }                                                                        \
    }                                                                          \
  }

// final stage on wave 0: merge 40 wave-candidates, extract top-1 and 10th
#define FINAL_MERGE10()                                                        \
  {                                                                            \
    _Pragma("unroll")                                                          \
    for (int r = 0; r < TOPK_K; ++r) {                                         \
      unsigned long long kmine = kl[0], kw = kl[0];                            \
      _Pragma("unroll")                                                        \
      for (int off = 32; off > 0; off >>= 1) {                                 \
        unsigned long long o = __shfl_xor(kw, off);                            \
        if (o > kw) kw = o;                                                    \
      }                                                                        \
      if (r == 0) maxv = __uint_as_float((unsigned)(kw >> 32) & 0x7fffffffu);  \
      if (r == TOPK_K - 1) {                                                   \
        Tv = __uint_as_float((unsigned)(kw >> 32) & 0x7fffffffu);              \
        Ti = (int)~(unsigned)(kw & 0xffffffffu);                               \
      }                                                                        \
      if (kmine == kw && kw != 0ull) {                                         \
        _Pragma("unroll")                                                      \
        for (int j = 0; j < TOPK_K - 1; ++j) kl[j] = kl[j + 1];                \
        kl[TOPK_K - 1] = 0ull;                                                 \
      }                                                                        \
    }                                                                          \
  }

// ---------------------------------------------------------------------------
// Kernel 0: zero cnt + ovf arrays (2*BM ints; ~2us, proven vs memset R6/R7).
// ---------------------------------------------------------------------------
__launch_bounds__(256)
__global__ void k_zero(int* __restrict__ p, int n) {
  for (int i = blockIdx.x * 256 + threadIdx.x; i < n; i += gridDim.x * 256) p[i] = 0;
}

// ---------------------------------------------------------------------------
// Kernel 1: SINGLE-PASS LDS-staged collect. Per positive: LDS atomicAdd rank
// + stage (a, n) in LDS (gather latency free-running, no ballots, no 2nd
// pass). Then one global atomic per (block,m) + linearized coalesced flush.
// Overflow (block-stage > SCAP or row > CAP) -> ovf[bm] -> select's rescan.
// ---------------------------------------------------------------------------
__launch_bounds__(CCH)
__global__ void k_collect(const float* __restrict__ pd_scores,
                          const float* __restrict__ pd_bboxes,
                          const int*   __restrict__ gt_labels,
                          const float* __restrict__ gt_bboxes,
                          const float* __restrict__ mask_gt,
                          int B, int N, int M, int C, int CAP,
                          int*    __restrict__ cnt,     // [B*M], pre-zeroed
                          int*    __restrict__ ovf,     // [B*M], pre-zeroed
                          float2* __restrict__ lists)   // [B*M*CAP]
{
  const int b = blockIdx.z;
  const int m0 = blockIdx.y * MG;
  const int mcount = min(MG, M - m0);
  const int tid = threadIdx.x;
  const int n = blockIdx.x * CCH + tid;

  __shared__ float4 sgt[MG];
  __shared__ int    sgl[MG];
  __shared__ int    smg[MG];
  __shared__ int    scnt[MG];
  __shared__ int    sgb[MG];      // global base per m
  __shared__ int    swr[MG];      // entries to write per m
  __shared__ int    sstart[MG];   // exclusive prefix of swr
  __shared__ int    stotal;
  __shared__ float2 stage[MG][SCAP];

  if (tid < mcount) {
    sgt[tid] = *(const float4*)(gt_bboxes + (size_t)(b * M + m0 + tid) * 4);
    sgl[tid] = min(max(gt_labels[b * M + m0 + tid], 0), C - 1);
    smg[tid] = (mask_gt[b * M + m0 + tid] > 0.0f) ? 1 : 0;
    scnt[tid] = 0;
  }
  __syncthreads();

  float4 p = make_float4(-1.f, -1.f, -2.f, -2.f);   // never overlaps
  if (n < N) p = *(const float4*)(pd_bboxes + ((size_t)b * N + n) * 4);
  const float* __restrict__ srow = pd_scores + ((size_t)b * N + n) * C;

  // ONE pass: overlap test -> IoU + gather + LDS stage (rank via LDS atomic)
  for (int mi = 0; mi < mcount; ++mi) {
    if (!smg[mi]) continue;
    const float4 g = sgt[mi];
    float ix1 = fmaxf(p.x, g.x), iy1 = fmaxf(p.y, g.y);
    float ix2 = fminf(p.z, g.z), iy2 = fminf(p.w, g.w);
    if (ix2 > ix1 && iy2 > iy1) {          // == (ov6>0 pre-underflow)
      Iou6 io = iou_pow6(p.x, p.y, p.z, p.w, g.x, g.y, g.z, g.w);
      float a = sigmoid_f(srow[sgl[mi]]) * io.ov6;   // identical expr everywhere
      int pos = atomicAdd(&scnt[mi], 1);
      if (pos < SCAP) stage[mi][pos] = make_float2(a, __int_as_float(n));
    }
  }
  __syncthreads();

  // reserve global space; detect overflow (stage cap or row cap)
  if (tid < mcount) {
    int c = scnt[tid];
    int w = min(c, SCAP);
    int gb = 0;
    if (w > 0) {
      gb = atomicAdd(&cnt[b * M + m0 + tid], w);
      if (gb + w > CAP) { atomicOr(&ovf[b * M + m0 + tid], 1); w = max(0, CAP - gb); }
    }
    if (c > SCAP) atomicOr(&ovf[b * M + m0 + tid], 1);
    sgb[tid] = gb;
    swr[tid] = w;
  }
  __syncthreads();
  if (tid == 0) {
    int acc = 0;
    for (int mi = 0; mi < mcount; ++mi) { sstart[mi] = acc; acc += swr[mi]; }
    stotal = acc;
  }
  __syncthreads();

  // linearized coalesced flush (~180 entries/block)
  const int tot = stotal;
  for (int i = tid; i < tot; i += CCH) {
    int mi = 0;
    while (mi + 1 < mcount && i >= sstart[mi + 1]) ++mi;   // 12-entry scan
    int off = i - sstart[mi];
    lists[(size_t)(b * M + m0 + mi) * CAP + sgb[mi] + off] = stage[mi][off];
  }
}

// ---------------------------------------------------------------------------
// Kernel 2: one block (256 thr) per (b,m): top-1 and 10th (value,index).
// R10's compact coalesced list path; exact full-row rescan fallback when
// cnt<10, cnt>CAP, ovf set, or selected T==0 (zero-tail needs global zeros).
// ---------------------------------------------------------------------------
__launch_bounds__(256)
__global__ void k_select(const float* __restrict__ pd_scores,
                         const float* __restrict__ pd_bboxes,
                         const int*   __restrict__ gt_labels,
                         const float* __restrict__ gt_bboxes,
                         const float* __restrict__ mask_gt,
                         int B, int N, int M, int C, int CAP,
                         const int*    __restrict__ cnt,
                         const int*    __restrict__ ovf,
                         const float2* __restrict__ lists,
                         float* __restrict__ maxv_out,   // [B*M]
                         float* __restrict__ t10v_out,   // [B*M]
                         int*   __restrict__ t10i_out)   // [B*M]
{
  const int m = blockIdx.x, b = blockIdx.y;
  const int bm = b * M + m;
  const int tid = threadIdx.x;
  const int lane = tid & 63;
  const int wid  = tid >> 6;

  __shared__ unsigned long long skey[4 * TOPK_K];
  __shared__ int sfb;

  if (mask_gt[bm] == 0.0f) {
    if (tid == 0) { maxv_out[bm] = 0.0f; t10v_out[bm] = 0.0f; t10i_out[bm] = -1; }
    return;
  }

  unsigned long long kl[TOPK_K];
#pragma unroll
  for (int j = 0; j < TOPK_K; ++j) kl[j] = 0ull;

  float maxv = 0.0f, Tv = 0.0f; int Ti = -1;
  const int c = cnt[bm];
  bool fb = (c < TOPK_K) || (c > CAP) || (ovf[bm] != 0);

  if (!fb) {
    const float2* __restrict__ lp = lists + (size_t)bm * CAP;
    for (int i = tid; i < c; i += 256) {
      float2 e = lp[i];
      unsigned long long k = mk_key(e.x, __float_as_int(e.y));
      KINSERT(k);
    }
    WAVE_MERGE10();
    __syncthreads();
    if (wid == 0) {
#pragma unroll
      for (int j = 0; j < TOPK_K; ++j) kl[j] = 0ull;
      kl[0] = (lane < 4 * TOPK_K) ? skey[lane] : 0ull;
      FINAL_MERGE10();
      if (lane == 0) sfb = (Tv == 0.0f) ? 1 : 0;  // zeros tied into top-10
    }
    __syncthreads();
    fb = (sfb != 0);
  }

  if (fb) {
    // exact full-row scan (zeros included, keyed stable) — cold path
#pragma unroll
    for (int j = 0; j < TOPK_K; ++j) kl[j] = 0ull;
    const float4 g = *(const float4*)(gt_bboxes + (size_t)bm * 4);
    int gl = min(max(gt_labels[bm], 0), C - 1);
    const float* __restrict__ srow = pd_scores + (size_t)b * N * C;
    const float4* __restrict__ pb = (const float4*)(pd_bboxes + (size_t)b * N * 4);
    for (int n = tid; n < N; n += 256) {
      float4 p = pb[n];
      Iou6 io = iou_pow6(p.x, p.y, p.z, p.w, g.x, g.y, g.z, g.w);
      unsigned long long kub = mk_key(io.ov6, 0);   // >= any key with value<=ov6
      if (kub > kl[TOPK_K - 1]) {
        float a = (io.ov6 == 0.0f) ? 0.0f
                                   : sigmoid_f(srow[(size_t)n * C + gl]) * io.ov6;
        unsigned long long k = mk_key(a, n);
        KINSERT(k);
      }
    }
    __syncthreads();   // skey reuse
    WAVE_MERGE10();
    __syncthreads();
    if (wid == 0) {
#pragma unroll
      for (int j = 0; j < TOPK_K; ++j) kl[j] = 0ull;
      kl[0] = (lane < 4 * TOPK_K) ? skey[lane] : 0ull;
      FINAL_MERGE10();
    }
  }

  if (tid == 0) { maxv_out[bm] = maxv; t10v_out[bm] = Tv; t10i_out[bm] = Ti; }
}

// ---------------------------------------------------------------------------
// Kernel 3: per-anchor assignment + all outputs. (R10 verbatim — proven 27us)
// 256 threads = 128 anchors x 2 m-halves; partials merged via LDS.
// Membership by rank test vs (T,I): a>T || (a==T && n<=I); zeros case n<=I.
// ---------------------------------------------------------------------------
__launch_bounds__(256)
__global__ void k_assign(const float* __restrict__ pd_scores,
                         const float* __restrict__ pd_bboxes,
                         const float* __restrict__ anchors,
                         const int*   __restrict__ gt_labels,
                         const float* __restrict__ gt_bboxes,
                         const float* __restrict__ mask_gt,
                         const float* __restrict__ maxv_in,
                         const float* __restrict__ t10v_in,
                         const int*   __restrict__ t10i_in,
                         int B, int N, int M, int C,
                         float* __restrict__ out)
{
  const int b = blockIdx.y;
  const int chunk0 = blockIdx.x * CH;
  const int tid = threadIdx.x;
  const int al   = tid & (CH - 1);   // anchor-local
  const int half = tid >> 7;         // which m-half this thread covers
  const int n = chunk0 + al;

  __shared__ float4 sgt[128];
  __shared__ int    sgl[128];
  __shared__ float  smg[128];
  __shared__ float  smpg[128];
  __shared__ float  spre[128];
  __shared__ float  smT[128];
  __shared__ int    smI[128];
  __shared__ int    skeep[128];
  __shared__ float  s_pov[CH];
  __shared__ int    s_parg[CH], s_pcnt[CH], s_pfirst[CH], s_pone[CH];
  __shared__ int    slab[CH];
  __shared__ float  ssv[CH];

  if (tid < M) {
    sgt[tid] = *(const float4*)(gt_bboxes + (size_t)(b * M + tid) * 4);
    sgl[tid] = min(max(gt_labels[b * M + tid], 0), C - 1);
    smg[tid] = mask_gt[b * M + tid];
    float mv  = maxv_in[b * M + tid];
    float mpg = fmaxf(mv, EPS_F);       // clip(align.max, EPS)
    smpg[tid] = mpg;
    spre[tid] = mpg * 0.999999f;        // q>=1 prefilter (below any rounding)
    smT[tid]  = t10v_in[b * M + tid];
    smI[tid]  = t10i_in[b * M + tid];
    skeep[tid] = (mv > EPS_F) ? 1 : 0;  // keep = topk max > EPS
  }
  __syncthreads();

  float* __restrict__ out_bbox   = out;
  float* __restrict__ out_scores = out + (size_t)B * N * 4;
  float* __restrict__ out_fg     = out_scores + (size_t)B * N * C;
  float* __restrict__ out_tgt    = out_fg + (size_t)B * N;

  const bool valid = (n < N);
  float pov = -1.0f; int parg = 0;
  int pcnt = 0, pfirst = -1, pone = 0;

  if (valid) {
    const float4 p = *(const float4*)(pd_bboxes + ((size_t)b * N + n) * 4);
    const float ax = anchors[(size_t)n * 2];
    const float ay = anchors[(size_t)n * 2 + 1];
    const float* __restrict__ srow = pd_scores + ((size_t)b * N + n) * C;

    const int mhalf = (M + 1) >> 1;
    const int mlo = half ? mhalf : 0;
    const int mhi = half ? M : mhalf;

    for (int m = mlo; m < mhi; ++m) {
      const float4 gbb = sgt[m];
      Iou6 io = iou_pow6(p.x, p.y, p.z, p.w, gbb.x, gbb.y, gbb.z, gbb.w);
      if (io.ov > pov) { pov = io.ov; parg = m; }   // first-occurrence argmax
      const float mgv = smg[m];
      if (mgv > 0.0f) {
        const float T = smT[m];
        const int keep = skeep[m];
        bool mem = false;
        const bool cand = keep && (io.ov6 > T);     // align < ov6 (sig<1)
        if (cand || (io.ov6 >= spre[m])) {
          const float a = sigmoid_f(srow[sgl[m]]) * io.ov6;  // == k_select's a
          if (cand) mem = (a > T) || (a == T && n <= smI[m]);
          if (a / smpg[m] >= 1.0f) pone = 1;        // int32(norm_align)==1
        } else if (keep && (T == 0.0f) && (io.ov6 == 0.0f)) {
          mem = (n <= smI[m]);                      // zero-valued tail of top-10
        }
        if (mem) {
          const float d = fminf(fminf(ax - gbb.x, ay - gbb.y),
                                fminf(gbb.z - ax, gbb.w - ay));
          if (d > EPS_F) { pcnt++; if (pfirst < 0) pfirst = m; }
        }
      }
    }
  }

  if (half == 1 && valid) {
    s_pov[al] = pov; s_parg[al] = parg; s_pcnt[al] = pcnt;
    s_pfirst[al] = pfirst; s_pone[al] = pone;
  }
  __syncthreads();

  if (half == 0 && valid) {
    // merge halves: half0 wins ov ties (lower m = first occurrence)
    float ov1 = s_pov[al];
    if (ov1 > pov) { pov = ov1; parg = s_parg[al]; }
    pcnt += s_pcnt[al];
    if (pfirst < 0) pfirst = s_pfirst[al];
    pone |= s_pone[al];

    float fg; int tgt;
    if (pcnt > 1)       { fg = 1.0f; tgt = parg; }     // where(multi, is_max, .)
    else if (pcnt == 1) { fg = 1.0f; tgt = pfirst; }
    else                { fg = 0.0f; tgt = 0; }        // argmax of zero row = 0

    slab[al] = sgl[tgt];
    ssv[al]  = (fg > 0.0f && pone) ? 1.0f : 0.0f;

    *(float4*)(out_bbox + ((size_t)b * N + n) * 4) = sgt[tgt];
    out_fg[(size_t)b * N + n]  = fg;
    out_tgt[(size_t)b * N + n] = (float)tgt;
  }
  __syncthreads();

  // cooperative coalesced write of the (rows x C) score tile
  const int rows = min(CH, N - chunk0);
  const int c4n = C >> 2;
  float4* __restrict__ os4 = (float4*)(out_scores + ((size_t)b * N + chunk0) * C);
  const int tot = rows * c4n;
  if (c4n == 20) {
    // C==80 fast path: i/20 via magic mul (runtime div = ~40-op libcall)
    for (int i = tid; i < tot; i += 256) {
      unsigned row = __umulhi((unsigned)i, 0xCCCCCCCDu) >> 4;
      int c0 = (i - (int)row * 20) * 4;
      int lr = slab[row]; float v = ssv[row];
      float4 o;
      o.x = (c0     == lr) ? v : 0.0f;
      o.y = (c0 + 1 == lr) ? v : 0.0f;
      o.z = (c0 + 2 == lr) ? v : 0.0f;
      o.w = (c0 + 3 == lr) ? v : 0.0f;
      os4[i] = o;
    }
  } else {
    for (int i = tid; i < tot; i += 256) {
      int row = i / c4n;
      int c0 = (i - row * c4n) * 4;
      int lr = slab[row]; float v = ssv[row];
      float4 o;
      o.x = (c0     == lr) ? v : 0.0f;
      o.y = (c0 + 1 == lr) ? v : 0.0f;
      o.z = (c0 + 2 == lr) ? v : 0.0f;
      o.w = (c0 + 3 == lr) ? v : 0.0f;
      os4[i] = o;
    }
  }
}

extern "C" void kernel_launch(void* const* d_in, const int* in_sizes, int n_in,
                              void* d_out, int out_size, void* d_ws, size_t ws_size,
                              hipStream_t stream) {
  const float* pd_scores = (const float*)d_in[0];
  const float* pd_bboxes = (const float*)d_in[1];
  const float* anchors   = (const float*)d_in[2];
  const int*   gt_labels = (const int*)d_in[3];
  const float* gt_bboxes = (const float*)d_in[4];
  const float* mask_gt   = (const float*)d_in[5];

  const int N = in_sizes[2] / 2;               // anchor_points (N,2)
  const int B = in_sizes[1] / (N * 4);         // pd_bboxes (B,N,4)
  const int M = in_sizes[3] / B;               // gt_labels (B,M,1)
  const int C = in_sizes[0] / (B * N);         // pd_scores (B,N,C)
  const int BM = B * M;

  char* ws = (char*)d_ws;
  float*  maxv  = (float*)ws;  ws += (size_t)BM * 4;
  float*  t10v  = (float*)ws;  ws += (size_t)BM * 4;
  int*    t10i  = (int*)ws;    ws += (size_t)BM * 4;
  int*    cnt   = (int*)ws;    ws += (size_t)BM * 4;
  int*    ovf   = (int*)ws;    ws += (size_t)BM * 4;
  float2* lists = (float2*)ws;

  const size_t header = (size_t)BM * 20;
  size_t avail = (ws_size > header) ? (ws_size - header) : 0;
  long long capll = (long long)(avail / ((size_t)BM * 8));
  int CAP = (int)((capll > 4096) ? 4096 : capll);
  if (CAP < 512) CAP = 0;   // small ws: rows take exact fallback in k_select

  k_zero<<<2, 256, 0, stream>>>(cnt, BM * 2);   // cnt and ovf are adjacent

  if (CAP > 0) {
    const int MGRP = (M + MG - 1) / MG;
    dim3 gc((N + CCH - 1) / CCH, MGRP, B);
    k_collect<<<gc, CCH, 0, stream>>>(pd_scores, pd_bboxes, gt_labels, gt_bboxes,
                                      mask_gt, B, N, M, C, CAP, cnt, ovf, lists);
  } else {
    // ensure ovf forces fallback when lists are unusable
    k_zero<<<1, 256, 0, stream>>>(cnt, BM);   // cnt stays 0 -> c<10 -> fallback
  }

  dim3 gs(M, B);
  k_select<<<gs, 256, 0, stream>>>(pd_scores, pd_bboxes, gt_labels, gt_bboxes,
                                   mask_gt, B, N, M, C, CAP, cnt, ovf, lists,
                                   maxv, t10v, t10i);

  dim3 g2((N + CH - 1) / CH, B);
  k_assign<<<g2, 256, 0, stream>>>(pd_scores, pd_bboxes, anchors, gt_labels,
                                   gt_bboxes, mask_gt, maxv, t10v, t10i,
                                   B, N, M, C, (float*)d_out);
}

// Round 15
// 74.685 us; speedup vs baseline: 4.3904x; 1.0434x over previous
//
#include <hip/hip_runtime.h>
#include <math.h>

#define TOPK_K 10
#define EPS_F 1e-9f
#define IOU_EPS_F 1e-7f
#define CH 128          // anchors per k_assign block
#define CCH 256         // anchors per k_collect block
#define MG 12           // GTs per collect m-group (M=96 -> MGRP=8)
#define SCAP 96         // LDS staging entries per (block, m)

struct Iou6 { float ov; float ov6; };

// NOTE: contract(off) so all kernels compute bit-identical IoU/align values.
// Membership (a==T) and the q>=1 test compare values computed in different
// kernels; any cross-kernel FMA-contraction difference would break equality.
__device__ __forceinline__ Iou6 iou_pow6(float px1, float py1, float px2, float py2,
                                         float gx1, float gy1, float gx2, float gy2) {
#pragma clang fp contract(off)
  float ix1 = fmaxf(px1, gx1);
  float iy1 = fmaxf(py1, gy1);
  float ix2 = fminf(px2, gx2);
  float iy2 = fminf(py2, gy2);
  float dw = fmaxf(ix2 - ix1, 0.0f);
  float dh = fmaxf(iy2 - iy1, 0.0f);
  float inter = dw * dh;
  float a1 = (px2 - px1) * (py2 - py1);
  float a2 = (gx2 - gx1) * (gy2 - gy1);
  float den = a1 + a2 - inter + IOU_EPS_F;
  float iou = inter / den;
  float ov = fmaxf(iou, 0.0f);
  float ov2 = ov * ov;
  Iou6 r; r.ov = ov; r.ov6 = ov2 * ov2 * ov2;
  return r;
}

__device__ __forceinline__ float sigmoid_f(float x) {
#pragma clang fp contract(off)
  return 1.0f / (1.0f + expf(-x));
}

// key: (ordered float bits << 32) | ~idx  -- larger = (bigger v, smaller idx).
// v >= 0 always; idx<0 -> sentinel key 0 (below every real key, incl. v==0).
__device__ __forceinline__ unsigned long long mk_key(float v, int idx) {
  if (idx < 0) return 0ull;
  unsigned uv = __float_as_uint(v) | 0x80000000u;
  return ((unsigned long long)uv << 32) | (unsigned)(~idx);
}

// stable top-10 key-ladder insert, all static indices (stays in VGPRs)
#define KINSERT(kk)                                                      \
  if ((kk) > kl[9]) {                                                    \
    _Pragma("unroll")                                                    \
    for (int j = 9; j >= 1; --j) {                                       \
      if ((kk) > kl[j - 1])      kl[j] = kl[j - 1];                      \
      else if ((kk) > kl[j])     kl[j] = (kk);                           \
    }                                                                    \
    if ((kk) > kl[0]) kl[0] = (kk);                                      \
  }

// wave-stage: 10 rounds of 64-lane key max + pop -> skey[wid*10+r]
#define WAVE_MERGE10()                                                         \
  {                                                                            \
    _Pragma("unroll")                                                          \
    for (int r = 0; r < TOPK_K; ++r) {                                         \
      unsigned long long kmine = kl[0], kw = kl[0];                            \
      _Pragma("unroll")                                                        \
      for (int off = 32; off > 0; off >>= 1) {                                 \
        unsigned long long o = __shfl_xor(kw, off);                            \
        if (o > kw) kw = o;                                                    \
      }                                                                        \
      if (lane == 0) skey[wid * TOPK_K + r] = kw;                              \
      if (kmine == kw && kw != 0ull) {  /* unique owner pops */                \
        _Pragma("unroll")                                                      \
        for (int j = 0; j < TOPK_K - 1; ++j) kl[j] = kl[j + 1];                \
        kl[TOPK_K - 1] = 0ull;                                                 \
      }                                                                        \
    }                                                                          \
  }

// final stage on wave 0: merge 40 wave-candidates, extract top-1 and 10th
#define FINAL_MERGE10()                                                        \
  {                                                                            \
    _Pragma("unroll")                                                          \
    for (int r = 0; r < TOPK_K; ++r) {                                         \
      unsigned long long kmine = kl[0], kw = kl[0];                            \
      _Pragma("unroll")                                                        \
      for (int off = 32; off > 0; off >>= 1) {                                 \
        unsigned long long o = __shfl_xor(kw, off);                            \
        if (o > kw) kw = o;                                                    \
      }                                                                        \
      if (r == 0) maxv = __uint_as_float((unsigned)(kw >> 32) & 0x7fffffffu);  \
      if (r == TOPK_K - 1) {                                                   \
        Tv = __uint_as_float((unsigned)(kw >> 32) & 0x7fffffffu);              \
        Ti = (int)~(unsigned)(kw & 0xffffffffu);                               \
      }                                                                        \
      if (kmine == kw && kw != 0ull) {                                         \
        _Pragma("unroll")                                                      \
        for (int j = 0; j < TOPK_K - 1; ++j) kl[j] = kl[j + 1];                \
        kl[TOPK_K - 1] = 0ull;                                                 \
      }                                                                        \
    }                                                                          \
  }

// ---------------------------------------------------------------------------
// Kernel 0: zero cnt + ovf arrays (2*BM ints; ~2us, proven vs memset R6/R7).
// ---------------------------------------------------------------------------
__launch_bounds__(256)
__global__ void k_zero(int* __restrict__ p, int n) {
  for (int i = blockIdx.x * 256 + threadIdx.x; i < n; i += gridDim.x * 256) p[i] = 0;
}

// ---------------------------------------------------------------------------
// Kernel 1: single-pass LDS-staged collect with BATCHED GATHERS.
// Pass A (fully unrolled, static reg indexing): all 12 overlap tests + ov6,
// and all 12 predicated score loads issued back-to-back -> 12 loads in
// flight per thread (MLP). Pass B: consume, LDS-rank, stage. One global
// atomic per (block,m) + linearized coalesced flush. Overflow -> ovf[bm].
// ---------------------------------------------------------------------------
__launch_bounds__(CCH)
__global__ void k_collect(const float* __restrict__ pd_scores,
                          const float* __restrict__ pd_bboxes,
                          const int*   __restrict__ gt_labels,
                          const float* __restrict__ gt_bboxes,
                          const float* __restrict__ mask_gt,
                          int B, int N, int M, int C, int CAP,
                          int*    __restrict__ cnt,     // [B*M], pre-zeroed
                          int*    __restrict__ ovf,     // [B*M], pre-zeroed
                          float2* __restrict__ lists)   // [B*M*CAP]
{
  const int b = blockIdx.z;
  const int m0 = blockIdx.y * MG;
  const int mcount = min(MG, M - m0);
  const int tid = threadIdx.x;
  const int n = blockIdx.x * CCH + tid;

  __shared__ float4 sgt[MG];
  __shared__ int    sgl[MG];
  __shared__ int    smg[MG];
  __shared__ int    scnt[MG];
  __shared__ int    sgb[MG];      // global base per m
  __shared__ int    swr[MG];      // entries to write per m
  __shared__ int    sstart[MG];   // exclusive prefix of swr
  __shared__ int    stotal;
  __shared__ float2 stage[MG][SCAP];

  if (tid < mcount) {
    sgt[tid] = *(const float4*)(gt_bboxes + (size_t)(b * M + m0 + tid) * 4);
    sgl[tid] = min(max(gt_labels[b * M + m0 + tid], 0), C - 1);
    smg[tid] = (mask_gt[b * M + m0 + tid] > 0.0f) ? 1 : 0;
    scnt[tid] = 0;
  }
  __syncthreads();

  float4 p = make_float4(-1.f, -1.f, -2.f, -2.f);   // never overlaps
  if (n < N) p = *(const float4*)(pd_bboxes + ((size_t)b * N + n) * 4);
  const float* __restrict__ srow = pd_scores + ((size_t)b * N + n) * C;

  // pass A: unrolled predicates + IoU + batched predicated gathers (MLP)
  float pv6[MG], psc[MG];
#pragma unroll
  for (int mi = 0; mi < MG; ++mi) {
    float v6 = 0.0f, sc = 0.0f;
    if (mi < mcount && smg[mi]) {
      const float4 g = sgt[mi];
      float ix1 = fmaxf(p.x, g.x), iy1 = fmaxf(p.y, g.y);
      float ix2 = fminf(p.z, g.z), iy2 = fminf(p.w, g.w);
      if (ix2 > ix1 && iy2 > iy1) {          // == (ov6>0 pre-underflow)
        Iou6 io = iou_pow6(p.x, p.y, p.z, p.w, g.x, g.y, g.z, g.w);
        v6 = io.ov6;
        sc = srow[sgl[mi]];                  // issued now, consumed in pass B
      }
    }
    pv6[mi] = v6; psc[mi] = sc;
  }

  // pass B: consume gathers, LDS-rank, stage. Underflow-zeros (v6==0 exact)
  // are excluded; select's Tv==0 rescan covers any row needing zero entries.
#pragma unroll
  for (int mi = 0; mi < MG; ++mi) {
    if (pv6[mi] > 0.0f) {
      float a = sigmoid_f(psc[mi]) * pv6[mi];   // identical expr everywhere
      int pos = atomicAdd(&scnt[mi], 1);
      if (pos < SCAP) stage[mi][pos] = make_float2(a, __int_as_float(n));
    }
  }
  __syncthreads();

  // reserve global space; detect overflow (stage cap or row cap)
  if (tid < mcount) {
    int c = scnt[tid];
    int w = min(c, SCAP);
    int gb = 0;
    if (w > 0) {
      gb = atomicAdd(&cnt[b * M + m0 + tid], w);
      if (gb + w > CAP) { atomicOr(&ovf[b * M + m0 + tid], 1); w = max(0, CAP - gb); }
    }
    if (c > SCAP) atomicOr(&ovf[b * M + m0 + tid], 1);
    sgb[tid] = gb;
    swr[tid] = w;
  }
  __syncthreads();
  if (tid == 0) {
    int acc = 0;
    for (int mi = 0; mi < mcount; ++mi) { sstart[mi] = acc; acc += swr[mi]; }
    stotal = acc;
  }
  __syncthreads();

  // linearized coalesced flush (~180 entries/block)
  const int tot = stotal;
  for (int i = tid; i < tot; i += CCH) {
    int mi = 0;
    while (mi + 1 < mcount && i >= sstart[mi + 1]) ++mi;   // 12-entry scan
    int off = i - sstart[mi];
    lists[(size_t)(b * M + m0 + mi) * CAP + sgb[mi] + off] = stage[mi][off];
  }
}

// ---------------------------------------------------------------------------
// Kernel 2: one block (256 thr) per (b,m): top-1 and 10th (value,index).
// R10's compact coalesced list path; exact full-row rescan fallback when
// cnt<10, cnt>CAP, ovf set, or selected T==0 (zero-tail needs global zeros).
// ---------------------------------------------------------------------------
__launch_bounds__(256)
__global__ void k_select(const float* __restrict__ pd_scores,
                         const float* __restrict__ pd_bboxes,
                         const int*   __restrict__ gt_labels,
                         const float* __restrict__ gt_bboxes,
                         const float* __restrict__ mask_gt,
                         int B, int N, int M, int C, int CAP,
                         const int*    __restrict__ cnt,
                         const int*    __restrict__ ovf,
                         const float2* __restrict__ lists,
                         float* __restrict__ maxv_out,   // [B*M]
                         float* __restrict__ t10v_out,   // [B*M]
                         int*   __restrict__ t10i_out)   // [B*M]
{
  const int m = blockIdx.x, b = blockIdx.y;
  const int bm = b * M + m;
  const int tid = threadIdx.x;
  const int lane = tid & 63;
  const int wid  = tid >> 6;

  __shared__ unsigned long long skey[4 * TOPK_K];
  __shared__ int sfb;

  if (mask_gt[bm] == 0.0f) {
    if (tid == 0) { maxv_out[bm] = 0.0f; t10v_out[bm] = 0.0f; t10i_out[bm] = -1; }
    return;
  }

  unsigned long long kl[TOPK_K];
#pragma unroll
  for (int j = 0; j < TOPK_K; ++j) kl[j] = 0ull;

  float maxv = 0.0f, Tv = 0.0f; int Ti = -1;
  const int c = cnt[bm];
  bool fb = (c < TOPK_K) || (c > CAP) || (ovf[bm] != 0);

  if (!fb) {
    const float2* __restrict__ lp = lists + (size_t)bm * CAP;
    for (int i = tid; i < c; i += 256) {
      float2 e = lp[i];
      unsigned long long k = mk_key(e.x, __float_as_int(e.y));
      KINSERT(k);
    }
    WAVE_MERGE10();
    __syncthreads();
    if (wid == 0) {
#pragma unroll
      for (int j = 0; j < TOPK_K; ++j) kl[j] = 0ull;
      kl[0] = (lane < 4 * TOPK_K) ? skey[lane] : 0ull;
      FINAL_MERGE10();
      if (lane == 0) sfb = (Tv == 0.0f) ? 1 : 0;  // zeros tied into top-10
    }
    __syncthreads();
    fb = (sfb != 0);
  }

  if (fb) {
    // exact full-row scan (zeros included, keyed stable) — cold path
#pragma unroll
    for (int j = 0; j < TOPK_K; ++j) kl[j] = 0ull;
    const float4 g = *(const float4*)(gt_bboxes + (size_t)bm * 4);
    int gl = min(max(gt_labels[bm], 0), C - 1);
    const float* __restrict__ srow = pd_scores + (size_t)b * N * C;
    const float4* __restrict__ pb = (const float4*)(pd_bboxes + (size_t)b * N * 4);
    for (int n = tid; n < N; n += 256) {
      float4 p = pb[n];
      Iou6 io = iou_pow6(p.x, p.y, p.z, p.w, g.x, g.y, g.z, g.w);
      unsigned long long kub = mk_key(io.ov6, 0);   // >= any key with value<=ov6
      if (kub > kl[TOPK_K - 1]) {
        float a = (io.ov6 == 0.0f) ? 0.0f
                                   : sigmoid_f(srow[(size_t)n * C + gl]) * io.ov6;
        unsigned long long k = mk_key(a, n);
        KINSERT(k);
      }
    }
    __syncthreads();   // skey reuse
    WAVE_MERGE10();
    __syncthreads();
    if (wid == 0) {
#pragma unroll
      for (int j = 0; j < TOPK_K; ++j) kl[j] = 0ull;
      kl[0] = (lane < 4 * TOPK_K) ? skey[lane] : 0ull;
      FINAL_MERGE10();
    }
  }

  if (tid == 0) { maxv_out[bm] = maxv; t10v_out[bm] = Tv; t10i_out[bm] = Ti; }
}

// ---------------------------------------------------------------------------
// Kernel 3: per-anchor assignment + all outputs. (R10/R14 verbatim)
// 256 threads = 128 anchors x 2 m-halves; partials merged via LDS.
// Membership by rank test vs (T,I): a>T || (a==T && n<=I); zeros case n<=I.
// ---------------------------------------------------------------------------
__launch_bounds__(256)
__global__ void k_assign(const float* __restrict__ pd_scores,
                         const float* __restrict__ pd_bboxes,
                         const float* __restrict__ anchors,
                         const int*   __restrict__ gt_labels,
                         const float* __restrict__ gt_bboxes,
                         const float* __restrict__ mask_gt,
                         const float* __restrict__ maxv_in,
                         const float* __restrict__ t10v_in,
                         const int*   __restrict__ t10i_in,
                         int B, int N, int M, int C,
                         float* __restrict__ out)
{
  const int b = blockIdx.y;
  const int chunk0 = blockIdx.x * CH;
  const int tid = threadIdx.x;
  const int al   = tid & (CH - 1);   // anchor-local
  const int half = tid >> 7;         // which m-half this thread covers
  const int n = chunk0 + al;

  __shared__ float4 sgt[128];
  __shared__ int    sgl[128];
  __shared__ float  smg[128];
  __shared__ float  smpg[128];
  __shared__ float  spre[128];
  __shared__ float  smT[128];
  __shared__ int    smI[128];
  __shared__ int    skeep[128];
  __shared__ float  s_pov[CH];
  __shared__ int    s_parg[CH], s_pcnt[CH], s_pfirst[CH], s_pone[CH];
  __shared__ int    slab[CH];
  __shared__ float  ssv[CH];

  if (tid < M) {
    sgt[tid] = *(const float4*)(gt_bboxes + (size_t)(b * M + tid) * 4);
    sgl[tid] = min(max(gt_labels[b * M + tid], 0), C - 1);
    smg[tid] = mask_gt[b * M + tid];
    float mv  = maxv_in[b * M + tid];
    float mpg = fmaxf(mv, EPS_F);       // clip(align.max, EPS)
    smpg[tid] = mpg;
    spre[tid] = mpg * 0.999999f;        // q>=1 prefilter (below any rounding)
    smT[tid]  = t10v_in[b * M + tid];
    smI[tid]  = t10i_in[b * M + tid];
    skeep[tid] = (mv > EPS_F) ? 1 : 0;  // keep = topk max > EPS
  }
  __syncthreads();

  float* __restrict__ out_bbox   = out;
  float* __restrict__ out_scores = out + (size_t)B * N * 4;
  float* __restrict__ out_fg     = out_scores + (size_t)B * N * C;
  float* __restrict__ out_tgt    = out_fg + (size_t)B * N;

  const bool valid = (n < N);
  float pov = -1.0f; int parg = 0;
  int pcnt = 0, pfirst = -1, pone = 0;

  if (valid) {
    const float4 p = *(const float4*)(pd_bboxes + ((size_t)b * N + n) * 4);
    const float ax = anchors[(size_t)n * 2];
    const float ay = anchors[(size_t)n * 2 + 1];
    const float* __restrict__ srow = pd_scores + ((size_t)b * N + n) * C;

    const int mhalf = (M + 1) >> 1;
    const int mlo = half ? mhalf : 0;
    const int mhi = half ? M : mhalf;

    for (int m = mlo; m < mhi; ++m) {
      const float4 gbb = sgt[m];
      Iou6 io = iou_pow6(p.x, p.y, p.z, p.w, gbb.x, gbb.y, gbb.z, gbb.w);
      if (io.ov > pov) { pov = io.ov; parg = m; }   // first-occurrence argmax
      const float mgv = smg[m];
      if (mgv > 0.0f) {
        const float T = smT[m];
        const int keep = skeep[m];
        bool mem = false;
        const bool cand = keep && (io.ov6 > T);     // align < ov6 (sig<1)
        if (cand || (io.ov6 >= spre[m])) {
          const float a = sigmoid_f(srow[sgl[m]]) * io.ov6;  // == k_select's a
          if (cand) mem = (a > T) || (a == T && n <= smI[m]);
          if (a / smpg[m] >= 1.0f) pone = 1;        // int32(norm_align)==1
        } else if (keep && (T == 0.0f) && (io.ov6 == 0.0f)) {
          mem = (n <= smI[m]);                      // zero-valued tail of top-10
        }
        if (mem) {
          const float d = fminf(fminf(ax - gbb.x, ay - gbb.y),
                                fminf(gbb.z - ax, gbb.w - ay));
          if (d > EPS_F) { pcnt++; if (pfirst < 0) pfirst = m; }
        }
      }
    }
  }

  if (half == 1 && valid) {
    s_pov[al] = pov; s_parg[al] = parg; s_pcnt[al] = pcnt;
    s_pfirst[al] = pfirst; s_pone[al] = pone;
  }
  __syncthreads();

  if (half == 0 && valid) {
    // merge halves: half0 wins ov ties (lower m = first occurrence)
    float ov1 = s_pov[al];
    if (ov1 > pov) { pov = ov1; parg = s_parg[al]; }
    pcnt += s_pcnt[al];
    if (pfirst < 0) pfirst = s_pfirst[al];
    pone |= s_pone[al];

    float fg; int tgt;
    if (pcnt > 1)       { fg = 1.0f; tgt = parg; }     // where(multi, is_max, .)
    else if (pcnt == 1) { fg = 1.0f; tgt = pfirst; }
    else                { fg = 0.0f; tgt = 0; }        // argmax of zero row = 0

    slab[al] = sgl[tgt];
    ssv[al]  = (fg > 0.0f && pone) ? 1.0f : 0.0f;

    *(float4*)(out_bbox + ((size_t)b * N + n) * 4) = sgt[tgt];
    out_fg[(size_t)b * N + n]  = fg;
    out_tgt[(size_t)b * N + n] = (float)tgt;
  }
  __syncthreads();

  // cooperative coalesced write of the (rows x C) score tile
  const int rows = min(CH, N - chunk0);
  const int c4n = C >> 2;
  float4* __restrict__ os4 = (float4*)(out_scores + ((size_t)b * N + chunk0) * C);
  const int tot = rows * c4n;
  if (c4n == 20) {
    // C==80 fast path: i/20 via magic mul (runtime div = ~40-op libcall)
    for (int i = tid; i < tot; i += 256) {
      unsigned row = __umulhi((unsigned)i, 0xCCCCCCCDu) >> 4;
      int c0 = (i - (int)row * 20) * 4;
      int lr = slab[row]; float v = ssv[row];
      float4 o;
      o.x = (c0     == lr) ? v : 0.0f;
      o.y = (c0 + 1 == lr) ? v : 0.0f;
      o.z = (c0 + 2 == lr) ? v : 0.0f;
      o.w = (c0 + 3 == lr) ? v : 0.0f;
      os4[i] = o;
    }
  } else {
    for (int i = tid; i < tot; i += 256) {
      int row = i / c4n;
      int c0 = (i - row * c4n) * 4;
      int lr = slab[row]; float v = ssv[row];
      float4 o;
      o.x = (c0     == lr) ? v : 0.0f;
      o.y = (c0 + 1 == lr) ? v : 0.0f;
      o.z = (c0 + 2 == lr) ? v : 0.0f;
      o.w = (c0 + 3 == lr) ? v : 0.0f;
      os4[i] = o;
    }
  }
}

extern "C" void kernel_launch(void* const* d_in, const int* in_sizes, int n_in,
                              void* d_out, int out_size, void* d_ws, size_t ws_size,
                              hipStream_t stream) {
  const float* pd_scores = (const float*)d_in[0];
  const float* pd_bboxes = (const float*)d_in[1];
  const float* anchors   = (const float*)d_in[2];
  const int*   gt_labels = (const int*)d_in[3];
  const float* gt_bboxes = (const float*)d_in[4];
  const float* mask_gt   = (const float*)d_in[5];

  const int N = in_sizes[2] / 2;               // anchor_points (N,2)
  const int B = in_sizes[1] / (N * 4);         // pd_bboxes (B,N,4)
  const int M = in_sizes[3] / B;               // gt_labels (B,M,1)
  const int C = in_sizes[0] / (B * N);         // pd_scores (B,N,C)
  const int BM = B * M;

  char* ws = (char*)d_ws;
  float*  maxv  = (float*)ws;  ws += (size_t)BM * 4;
  float*  t10v  = (float*)ws;  ws += (size_t)BM * 4;
  int*    t10i  = (int*)ws;    ws += (size_t)BM * 4;
  int*    cnt   = (int*)ws;    ws += (size_t)BM * 4;
  int*    ovf   = (int*)ws;    ws += (size_t)BM * 4;
  float2* lists = (float2*)ws;

  const size_t header = (size_t)BM * 20;
  size_t avail = (ws_size > header) ? (ws_size - header) : 0;
  long long capll = (long long)(avail / ((size_t)BM * 8));
  int CAP = (int)((capll > 4096) ? 4096 : capll);
  if (CAP < 512) CAP = 0;   // small ws: rows take exact fallback in k_select

  k_zero<<<2, 256, 0, stream>>>(cnt, BM * 2);   // cnt and ovf are adjacent

  if (CAP > 0) {
    const int MGRP = (M + MG - 1) / MG;
    dim3 gc((N + CCH - 1) / CCH, MGRP, B);
    k_collect<<<gc, CCH, 0, stream>>>(pd_scores, pd_bboxes, gt_labels, gt_bboxes,
                                      mask_gt, B, N, M, C, CAP, cnt, ovf, lists);
  }

  dim3 gs(M, B);
  k_select<<<gs, 256, 0, stream>>>(pd_scores, pd_bboxes, gt_labels, gt_bboxes,
                                   mask_gt, B, N, M, C, CAP, cnt, ovf, lists,
                                   maxv, t10v, t10i);

  dim3 g2((N + CH - 1) / CH, B);
  k_assign<<<g2, 256, 0, stream>>>(pd_scores, pd_bboxes, anchors, gt_labels,
                                   gt_bboxes, mask_gt, maxv, t10v, t10i,
                                   B, N, M, C, (float*)d_out);
}